// Round 11
// baseline (172.562 us; speedup 1.0000x reference)
//
#include <hip/hip_runtime.h>
#include <hip/hip_fp16.h>

// LBP semantic dependency, channel-difference form, base-2 domain.
//   d'(x,p) = sp(x+p) - sp(x);  db[a,u] = edge + sum_{v!=a,u} sum_t d'-terms
// All db quantities in units of ln2. tp = e^p quantized fp16.
// R19 = SINGLE-SLAB BLOCK, 2 BLOCKS/CU, GRID 320 (no idle CUs):
//   R18 decoded the occupancy counter: grid 160 left 96 CUs idle; R14-R17's
//   ~26% was (256+64)/2 CU-coverage x 15 waves. Per-slice stall (75%) never
//   moved because 155KB LDS => 1 block/CU => nothing hides restage/barrier/
//   finalize. Fix: one 160x162 fp16 slab (51.8KB, LDS tot 62.4KB) => 2
//   blocks/CU co-resident (20 waves/CU), grid 320 in ONE round; the other
//   block's issue covers this block's stalls. Slab-cached t-order
//   (A:..2 | B:2,0,1 | C:1,2,0) => only 4 restages/slice, L3-warm.
//   di-terms captured to rowA/colA/diagA during phase-A stream (same fp16
//   quantization point -> numerics preserved). ph1 product split 5+5.

#define S    160
#define S2   25600            // 160*160
#define S3   4096000          // 160^3 (per-n slab, elements)
#define STR  162              // LDS slab row stride in halves (bank-spread pad)
#define C2E  1.4426950408889634f

__device__ __forceinline__ float fexp2(float x) { return __builtin_amdgcn_exp2f(x); }
__device__ __forceinline__ float flog2(float x) { return __builtin_amdgcn_logf(x); }
__device__ __forceinline__ float cdb(float x) {
    return fminf(fmaxf(x, -45.f), 45.f);  // saturated beyond ~30 either way;
}                                         // keeps folded/paired terms in fp32
__device__ __forceinline__ float sp2t(float tp) { return flog2(1.f + tp); }
__device__ __forceinline__ float Ff(float x, float tp) {
    float tx = fexp2(x);
    return flog2(1.f + tx * tp) - flog2(1.f + tx);
}
__device__ __forceinline__ const float* selT(int t, const float* a,
                                             const float* b, const float* c) {
    return (t == 0) ? a : (t == 1) ? b : c;
}
__device__ __forceinline__ __half hsel(__half2 h01, __half2 h23, int c) {
    return (c == 0) ? h01.x : (c == 1) ? h01.y : (c == 2) ? h23.x : h23.y;
}

// One block per slice (n,a). 640 threads (10 waves), 62,400B LDS -> 2 blk/CU,
// grid 320 <= 512 slots -> single round, all CUs covered.
__global__ __launch_bounds__(640)
void k_fused(const float* __restrict__ s_sib, const float* __restrict__ s_cop,
             const float* __restrict__ s_grd, const float* __restrict__ s_edge,
             float* __restrict__ outp)
{
    int slice = blockIdx.x;               // 0..319
    int a = slice % S, n = slice / S;
    int tid = threadIdx.x;
    int u4 = tid % 40, r = tid / 40;      // staging map (r 0..15, v = r+16i)
    int us = tid % S,  vs = tid / S;      // sweep map   (vs 0..3, v = 4k+vs)

    __shared__ __half slab[S * STR];      // ONE tensor's tp[v][u]  (51,840 B)
    __shared__ float  scr[1280];          // ph1 / sweep partials     (5,120 B)
    __shared__ float  db1s[S], db2s[S], E1[S], E2[S];               // (2,560 B)
    __shared__ __half rowA[3][S], colA[3][S], diagA[3][S];          // (2,880 B)

    const int aq = a >> 2, ac = a & 3;

    // ---- phase A: ph1 stream over all 3 t (global->reg, product-partials);
    // slab stores only t=2 (phase B's first tensor); di-term captures.
    float4 acc = make_float4(0.f, 0.f, 0.f, 0.f);
    #pragma unroll
    for (int t = 0; t < 3; ++t) {
        const float* g = selT(t, s_sib, s_cop, s_grd)
                       + (long)n * S3 + (long)a * S + u4 * 4;
        float4 pv[10];
        #pragma unroll
        for (int i = 0; i < 10; ++i)
            pv[i] = *(const float4*)(g + (long)(r + 16 * i) * S2);
        float4 P = make_float4(1.f, 1.f, 1.f, 1.f);
        float4 Q = make_float4(1.f, 1.f, 1.f, 1.f);
        #pragma unroll
        for (int i = 0; i < 10; ++i) {
            int v = r + 16 * i;
            float t0 = fexp2(pv[i].x * C2E), t1 = fexp2(pv[i].y * C2E);
            float t2 = fexp2(pv[i].z * C2E), t3 = fexp2(pv[i].w * C2E);
            if (i < 5) {
                P.x = __builtin_fmaf(P.x, t0, P.x);
                P.y = __builtin_fmaf(P.y, t1, P.y);
                P.z = __builtin_fmaf(P.z, t2, P.z);
                P.w = __builtin_fmaf(P.w, t3, P.w);
            } else {
                Q.x = __builtin_fmaf(Q.x, t0, Q.x);
                Q.y = __builtin_fmaf(Q.y, t1, Q.y);
                Q.z = __builtin_fmaf(Q.z, t2, Q.z);
                Q.w = __builtin_fmaf(Q.w, t3, Q.w);
            }
            __half2 h01 = __floats2half2_rn(t0, t1);
            __half2 h23 = __floats2half2_rn(t2, t3);
            if (t == 2) {
                uint2 w; w.x = *(unsigned*)&h01; w.y = *(unsigned*)&h23;
                *(uint2*)(&slab[v * STR + u4 * 4]) = w;
            }
            if (v == a) {                       // tp(a, u): 40 threads
                uint2 w; w.x = *(unsigned*)&h01; w.y = *(unsigned*)&h23;
                *(uint2*)(&rowA[t][u4 * 4]) = w;
            }
            if (u4 == aq) colA[t][v] = hsel(h01, h23, ac);        // tp(v=..., a)
            if (u4 == (v >> 2)) diagA[t][v] = hsel(h01, h23, v & 3); // tp(v,v)
        }
        acc.x += flog2(P.x) + flog2(Q.x);
        acc.y += flog2(P.y) + flog2(Q.y);
        acc.z += flog2(P.z) + flog2(Q.z);
        acc.w += flog2(P.w) + flog2(Q.w);
    }
    float edg = 0.f;
    if (tid < S) edg = s_edge[(long)n * S2 + tid * S + a] * C2E;
    __syncthreads();
    // ph1 reduce: 16 r-groups -> 8 (one RMW stage)
    float4* scr4 = (float4*)scr;
    if (r < 8) scr4[r * 40 + u4] = acc;
    __syncthreads();
    if (r >= 8) {
        float4 o = scr4[(r - 8) * 40 + u4];
        o.x += acc.x; o.y += acc.y; o.z += acc.z; o.w += acc.w;
        scr4[(r - 8) * 40 + u4] = o;
    }
    __syncthreads();
    // db1 + E1 (exclusions from captured quantized values)
    if (tid < S) {
        int u = tid;
        float s = 0.f;
        #pragma unroll
        for (int g2 = 0; g2 < 8; ++g2) s += scr[(g2 * 40 + (u >> 2)) * 4 + (u & 3)];
        float rr = edg + s - 480.f;
        #pragma unroll
        for (int t = 0; t < 3; ++t) {
            float tpa = __half2float(rowA[t][u]);
            rr -= (sp2t(tpa) - 1.f);
            if (u != a) {
                float tpu = __half2float(diagA[t][u]);
                rr -= (sp2t(tpu) - 1.f);
            }
        }
        db1s[u] = rr;
        E1[u] = fexp2(cdb(rr) + 1.f);
    }
    __syncthreads();

    // ---- phase B: d2 sweep, t-order 2(cached), 0, 1
    float d2acc = 0.f;
    #pragma unroll 1
    for (int tt = 0; tt < 3; ++tt) {
        int t = (tt == 0) ? 2 : tt - 1;
        if (tt != 0) {                    // restage tensor t (L3-warm)
            __syncthreads();              // prior sweep done reading slab
            const float* g = selT(t, s_sib, s_cop, s_grd)
                           + (long)n * S3 + (long)a * S + u4 * 4;
            float4 pv[10];
            #pragma unroll
            for (int i = 0; i < 10; ++i)
                pv[i] = *(const float4*)(g + (long)(r + 16 * i) * S2);
            #pragma unroll
            for (int i = 0; i < 10; ++i) {
                float t0 = fexp2(pv[i].x * C2E), t1 = fexp2(pv[i].y * C2E);
                float t2 = fexp2(pv[i].z * C2E), t3 = fexp2(pv[i].w * C2E);
                __half2 h01 = __floats2half2_rn(t0, t1);
                __half2 h23 = __floats2half2_rn(t2, t3);
                uint2 w; w.x = *(unsigned*)&h01; w.y = *(unsigned*)&h23;
                *(uint2*)(&slab[(r + 16 * i) * STR + u4 * 4]) = w;
            }
            __syncthreads();
        }
        // folded + paired d2 terms: v = kb*16 + j*4 + vs
        for (int kb = 0; kb < 10; ++kb) {
            float tA[4], tB[4], Ev[4], nm[4], dn[4];
            #pragma unroll
            for (int j = 0; j < 4; ++j) {
                int v = kb * 16 + j * 4 + vs;
                tA[j] = __half2float(slab[v * STR + us]);
                tB[j] = __half2float(slab[us * STR + v]);
                Ev[j] = E1[v];
            }
            #pragma unroll
            for (int j = 0; j < 4; ++j) {
                float B1 = 1.f + tB[j];
                nm[j] = __builtin_fmaf(Ev[j], tA[j], B1);
                dn[j] = B1 + Ev[j];
            }
            d2acc += flog2(nm[0] * nm[1]) - flog2(dn[0] * dn[1]);
            d2acc += flog2(nm[2] * nm[3]) - flog2(dn[2] * dn[3]);
        }
    }
    scr[vs * S + us] = d2acc;
    __syncthreads();
    // db2 (inline di2 from captures) + E2
    if (tid < S) {
        int u = tid;
        float sw = scr[u] + scr[S + u] + scr[2 * S + u] + scr[3 * S + u];
        float db1a1 = cdb(db1s[a]) + 1.f;
        float db1u1 = cdb(db1s[u]) + 1.f;
        float sum = 0.f;
        #pragma unroll
        for (int t = 0; t < 3; ++t) {
            float tpa  = __half2float(rowA[t][u]);
            float tpba = __half2float(colA[t][u]);
            sum += Ff(db1a1 - sp2t(tpba), tpa);           // C2(v=a)
            if (u != a) {
                float tpu = __half2float(diagA[t][u]);
                sum += Ff(db1u1 - sp2t(tpu), tpu);        // C2(v=u)
            }
        }
        float d2v = edg - sum + sw;
        db2s[u] = d2v;
        E2[u] = fexp2(cdb(d2v));
    }
    __syncthreads();

    // ---- phase C: d3 sweep, t-order 1(cached), 2, 0
    float d3acc = 0.f;
    float E1u = E1[us];
    #pragma unroll 1
    for (int tt = 0; tt < 3; ++tt) {
        int t = (tt == 0) ? 1 : (tt == 1) ? 2 : 0;
        if (tt != 0) {
            __syncthreads();
            const float* g = selT(t, s_sib, s_cop, s_grd)
                           + (long)n * S3 + (long)a * S + u4 * 4;
            float4 pv[10];
            #pragma unroll
            for (int i = 0; i < 10; ++i)
                pv[i] = *(const float4*)(g + (long)(r + 16 * i) * S2);
            #pragma unroll
            for (int i = 0; i < 10; ++i) {
                float t0 = fexp2(pv[i].x * C2E), t1 = fexp2(pv[i].y * C2E);
                float t2 = fexp2(pv[i].z * C2E), t3 = fexp2(pv[i].w * C2E);
                __half2 h01 = __floats2half2_rn(t0, t1);
                __half2 h23 = __floats2half2_rn(t2, t3);
                uint2 w; w.x = *(unsigned*)&h01; w.y = *(unsigned*)&h23;
                *(uint2*)(&slab[(r + 16 * i) * STR + u4 * 4]) = w;
            }
            __syncthreads();
        }
        for (int kb = 0; kb < 10; ++kb) {
            float tA[4], tB[4], Ev[4];
            #pragma unroll
            for (int j = 0; j < 4; ++j) {
                int v = kb * 16 + j * 4 + vs;
                tA[j] = __half2float(slab[v * STR + us]);
                tB[j] = __half2float(slab[us * STR + v]);
                Ev[j] = E2[v];
            }
            #pragma unroll
            for (int j = 0; j < 4; ++j) {
                float A1 = 1.f + tA[j];
                float q  = A1 + E1u;
                float rr = __builtin_fmaf(E1u, tB[j], A1);
                float p  = Ev[j] * q;
                float nm = __builtin_fmaf(p, tA[j], rr);
                float dn = rr + p;
                d3acc += flog2(nm) - flog2(dn);
            }
        }
    }
    scr[vs * S + us] = d3acc;
    __syncthreads();
    // ---- di3 + output
    if (tid < S) {
        int u = tid;
        float sw = scr[u] + scr[S + u] + scr[2 * S + u] + scr[3 * S + u];
        float db1u1 = cdb(db1s[u]) + 1.f;
        float db2a = cdb(db2s[a]);
        float db2u = cdb(db2s[u]);
        float sum = 0.f;
        #pragma unroll
        for (int t = 0; t < 3; ++t) {
            float tpa  = __half2float(rowA[t][u]);
            float tpba = __half2float(colA[t][u]);
            float d2vu = Ff(db1u1 - sp2t(tpa), tpba);
            sum += Ff(db2a - d2vu, tpa);                  // C3(v=a)
            if (u != a) {
                float tpu = __half2float(diagA[t][u]);
                float d2  = Ff(db1u1 - sp2t(tpu), tpu);
                sum += Ff(db2u - d2, tpu);                // C3(v=u)
            }
        }
        float s = edg - sum + sw;
        float sc  = fminf(fmaxf(s, -60.f), 60.f);  // avoid exp2 overflow -> inf*0=NaN
        float tsg = fexp2(-sc);
        float rr  = __fdividef(1.f, 1.f + tsg);
        long ob = ((long)(n * S + u) * S + a) * 2;
        *(float2*)(outp + ob) = make_float2(tsg * rr, rr);
    }
}

extern "C" void kernel_launch(void* const* d_in, const int* in_sizes, int n_in,
                              void* d_out, int out_size, void* d_ws, size_t ws_size,
                              hipStream_t stream) {
    const float* s_edge = (const float*)d_in[0];
    const float* s_sib  = (const float*)d_in[1];
    const float* s_cop  = (const float*)d_in[2];
    const float* s_grd  = (const float*)d_in[3];
    float* outp = (float*)d_out;
    (void)d_ws; (void)ws_size;          // workspace unused (no poison fills)

    k_fused<<<320, 640, 0, stream>>>(s_sib, s_cop, s_grd, s_edge, outp);
}